// Round 10
// baseline (314.841 us; speedup 1.0000x reference)
//
#include <hip/hip_runtime.h>
#include <hip/hip_bf16.h>
#include <cstddef>
#include <cstdint>

// ---------- types / helpers ----------
typedef short short8 __attribute__((ext_vector_type(8)));
typedef __bf16 bf16x8 __attribute__((ext_vector_type(8)));
typedef float f4 __attribute__((ext_vector_type(4)));

__device__ __forceinline__ short f2b(float f) {
    __hip_bfloat16 h = __float2bfloat16(f);
    return __builtin_bit_cast(short, h);
}
__device__ __forceinline__ f4 mfma16(short8 a, short8 b, f4 c) {
    return __builtin_amdgcn_mfma_f32_16x16x32_bf16(
        __builtin_bit_cast(bf16x8, a), __builtin_bit_cast(bf16x8, b), c, 0, 0, 0);
}
__device__ __forceinline__ float b2f(short s) {
    unsigned u = ((unsigned)(unsigned short)s) << 16;
    return __builtin_bit_cast(float, u);
}
// async 16B/lane global->LDS (lds dest = wave-uniform base + lane*16)
__device__ __forceinline__ void gl_lds16(const void* g, void* l) {
    __builtin_amdgcn_global_load_lds(
        (const __attribute__((address_space(1))) unsigned*)g,
        (__attribute__((address_space(3))) unsigned*)l, 16, 0, 0);
}
// XOR swizzle on 8-short (16B) chunk index
__device__ __forceinline__ int swc8(int row) { return (row ^ (row >> 3)) & 7; }

// Problem constants
#define BATCH 2
#define SEQ   2048
#define HID   2048
#define NH    16
#define NKV   4
#define HD    128
#define KVD   512

// ---------- fused f32 -> bf16 convert of X, Wq, Wk, Wv + RoPE trig table + counter reset ----------
__global__ void cvt4_kernel(const float* __restrict__ X,  const float* __restrict__ Wq,
                            const float* __restrict__ Wk, const float* __restrict__ Wv,
                            short* __restrict__ dst, float* __restrict__ tab,
                            int* __restrict__ cnt)
{
    int i = blockIdx.x * 256 + threadIdx.x;        // chunk of 8 elems; 1,835,008 total
    if (i == 0) *cnt = 0;                          // flash work-stealing counter reset
    if (i < SEQ * 64) {                            // fill cos/sin table [pos][j] (131072)
        int pos = i >> 6, jj = i & 63;
        float invf = exp2f(-(float)jj * (19.931568569324174f / 64.0f)); // theta^(-j/64)
        float ang  = (float)pos * invf;
        float sn, cs;
        sincosf(ang, &sn, &cs);
        ((float2*)tab)[i] = make_float2(cs, sn);
    }
    const float* src; int si;
    if (i < 1048576)      { src = X;  si = i; }
    else if (i < 1572864) { src = Wq; si = i - 1048576; }
    else if (i < 1703936) { src = Wk; si = i - 1572864; }
    else                  { src = Wv; si = i - 1703936; }
    f4 v0 = *(const f4*)&src[si * 8];
    f4 v1 = *(const f4*)&src[si * 8 + 4];
    short8 r;
#pragma unroll
    for (int j = 0; j < 4; ++j) { r[j] = f2b(v0[j]); r[4 + j] = f2b(v1[j]); }
    *(short8*)&dst[(size_t)i * 8] = r;
}

__global__ void cvt_kernel(const float* __restrict__ src, short* __restrict__ dst, int n8)
{
    int i = blockIdx.x * 256 + threadIdx.x;
    if (i >= n8) return;
    f4 v0 = *(const f4*)&src[i * 8];
    f4 v1 = *(const f4*)&src[i * 8 + 4];
    short8 r;
#pragma unroll
    for (int j = 0; j < 4; ++j) { r[j] = f2b(v0[j]); r[4 + j] = f2b(v1[j]); }
    *(short8*)&dst[i * 8] = r;
}

// ---------- shared GEMM mainloop (m97-class): 128x128 tile, gl_lds + src-permuted swizzle ----------
__device__ __forceinline__ void gemm_core(
    const short* __restrict__ A, const short* __restrict__ W, int K,
    int mbase, int nbase, short* a_lds, short* b_lds, f4 (*acc)[4])
{
    const int tid  = threadIdx.x;
    const int lane = tid & 63;
    const int wave = tid >> 6;
    const int quad = lane >> 4;
    const int l15  = lane & 15;
    const int wrow = (wave >> 1) * 64;
    const int wcol = (wave & 1) * 64;
    const int srow = wave * 8 + (lane >> 3);   // + s*32
    const int c8   = lane & 7;

    for (int kb = 0; kb < K; kb += 64) {
#pragma unroll
        for (int s = 0; s < 4; ++s) {
            int row = s * 32 + srow;
            int g   = c8 ^ swc8(row);
            gl_lds16(&A[(size_t)(mbase + row) * K + kb + g * 8], &a_lds[(s * 32 + wave * 8) * 64]);
            gl_lds16(&W[(size_t)(nbase + row) * K + kb + g * 8], &b_lds[(s * 32 + wave * 8) * 64]);
        }
        __syncthreads();
#pragma unroll
        for (int kk = 0; kk < 64; kk += 32) {
            short8 af[4], bf[4];
#pragma unroll
            for (int i = 0; i < 4; ++i) {
                int row = wrow + i * 16 + l15;
                af[i] = *(const short8*)&a_lds[row * 64 + ((kk + quad * 8) ^ (swc8(row) << 3))];
            }
#pragma unroll
            for (int j = 0; j < 4; ++j) {
                int row = wcol + j * 16 + l15;
                bf[j] = *(const short8*)&b_lds[row * 64 + ((kk + quad * 8) ^ (swc8(row) << 3))];
            }
#pragma unroll
            for (int i = 0; i < 4; ++i)
#pragma unroll
                for (int j = 0; j < 4; ++j)
                    acc[i][j] = mfma16(af[i], bf[j], acc[i][j]);
        }
        __syncthreads();
    }
}

// ---------- fused QKV projection + RoPE (Q/K) ----------
__global__ __launch_bounds__(256, 3) void qkv_gemm(
    const short* __restrict__ xb,
    const short* __restrict__ wqb, const short* __restrict__ wkb, const short* __restrict__ wvb,
    const float* __restrict__ bq, const float* __restrict__ bk, const float* __restrict__ bv,
    short* __restrict__ q_ws, short* __restrict__ k_ws, short* __restrict__ vt_ws,
    const float* __restrict__ tab)
{
    __shared__ short a_lds[128 * 64];
    __shared__ short b_lds[128 * 64];
    const int nblk = blockIdx.x;
    const short* W; const float* bias; int nb, mode;
    if (nblk < 16)      { W = wqb; bias = bq; nb = nblk;      mode = 0; }
    else if (nblk < 20) { W = wkb; bias = bk; nb = nblk - 16; mode = 1; }
    else                { W = wvb; bias = bv; nb = nblk - 20; mode = 2; }
    const int mbase = blockIdx.y * 128;
    const int nbase = nb * 128;

    f4 acc[4][4] = {};
    gemm_core(xb, W, HID, mbase, nbase, a_lds, b_lds, acc);

    const int lane = threadIdx.x & 63;
    const int wave = threadIdx.x >> 6;
    const int quad = lane >> 4;
    const int l15  = lane & 15;
    const int wrow = (wave >> 1) * 64;
    const int wcol = (wave & 1) * 64;

    float bb[4];
#pragma unroll
    for (int j = 0; j < 4; ++j) bb[j] = bias[nbase + wcol + j * 16 + l15];

    if (mode == 2) {           // V: write transposed vt[b][kvh][d][s]
#pragma unroll
        for (int i = 0; i < 4; ++i)
#pragma unroll
            for (int j = 0; j < 4; ++j) {
                int n = nbase + wcol + j * 16 + l15;
                int kvh = n >> 7, d = n & 127;
#pragma unroll
                for (int r = 0; r < 4; ++r) {
                    int m = mbase + wrow + i * 16 + quad * 4 + r;
                    int b = m >> 11, s = m & (SEQ - 1);
                    vt_ws[(((size_t)(b * NKV + kvh) * HD + d) << 11) + s] = f2b(acc[i][j][r] + bb[j]);
                }
            }
    } else {
        short* out = (mode == 0) ? q_ws : k_ws;
        const int N = (mode == 0) ? HID : KVD;
        const float2* tp = (const float2*)tab;

        // publish biased values (bf16) for the cross-wave half exchange:
        // col c<64 -> a_lds[m][c], c>=64 -> b_lds[m][c-64]
#pragma unroll
        for (int i = 0; i < 4; ++i)
#pragma unroll
            for (int j = 0; j < 4; ++j) {
                int c  = wcol + j * 16 + l15;
                short* sm = (c < 64) ? a_lds : b_lds;
                int cc = c & 63;
#pragma unroll
                for (int r = 0; r < 4; ++r) {
                    int ml = wrow + i * 16 + quad * 4 + r;
                    sm[ml * 64 + cc] = f2b(acc[i][j][r] + bb[j]);
                }
            }
        __syncthreads();

#pragma unroll
        for (int i = 0; i < 4; ++i)
#pragma unroll
            for (int j = 0; j < 4; ++j) {
                int c   = wcol + j * 16 + l15;      // d = n & 127
                int n   = nbase + c;
                int j64 = c & 63;
                const short* smp = (c < 64) ? b_lds : a_lds;   // partner half (c^64)
#pragma unroll
                for (int r = 0; r < 4; ++r) {
                    int ml  = wrow + i * 16 + quad * 4 + r;
                    int m   = mbase + ml;
                    int pos = m & (SEQ - 1);
                    float2 t2 = tp[pos * 64 + j64];
                    float own = acc[i][j][r] + bb[j];
                    float pv  = b2f(smp[ml * 64 + j64]);
                    float o   = (c < 64) ? (own * t2.x - pv * t2.y)
                                         : (own * t2.x + pv * t2.y);
                    out[(size_t)m * N + n] = f2b(o);
                }
            }
    }
}

// ---------- output projection, 8-phase 256x128 template (T3+T4+T2+T5) ----------
// 512 thr = 8 waves (2M x 4N); BM=256 BN=128 BK=64; grid 16x16 = 256 blocks =
// 1/CU (LDS 96KB). Per wave: 128x32 C-tile = acc[8][2]. Per K-tile: 4 phases x
// {2 gl_lds staging of t+1 -> buf^1, 4 ds_read A-quadrant, raw s_barrier,
// setprio(1), 8 MFMA, setprio(0), raw s_barrier}. B-frags (4 ds_read) loaded
// once per K-tile, held in regs. The ONLY correctness-critical sync is the
// iter-top __syncthreads (drains staging vmcnt; same semantics as gemm_core) —
// phase barriers are scheduling-only: phases read buf, staging writes buf^1,
// no data crosses them (m152 race class structurally excluded). Staged loads
// get 1-3 phases of flight before the drain (T3's counted-flight mechanism).
// Addressing + swc8 both-sides swizzle lifted verbatim from proven gemm_core.
__global__ __launch_bounds__(512, 2) void out_gemm8(
    const short* __restrict__ A, const short* __restrict__ W, float* __restrict__ C)
{
    __shared__ __align__(16) short a_lds[2][256 * 64];   // 64 KB
    __shared__ __align__(16) short b_lds[2][128 * 64];   // 32 KB

    // XCD-chunked work swizzle (bijective: 256 blocks % 8 == 0)
    const int bid = blockIdx.y * 16 + blockIdx.x;
    const int swz = (bid & 7) * 32 + (bid >> 3);
    const int mbase = (swz >> 4) * 256;
    const int nbase = (swz & 15) * 128;

    const int tid  = threadIdx.x;
    const int lane = tid & 63;
    const int wave = tid >> 6;       // 0..7
    const int quad = lane >> 4;
    const int l15  = lane & 15;
    const int wm   = wave >> 2;      // 0..1 (M half)
    const int wn   = wave & 3;       // 0..3 (N quarter)
    const int srow8 = tid >> 3;      // 0..63
    const int c8    = tid & 7;

    f4 acc[8][2] = {};

    // prologue: stage tile 0 -> buf 0 (A: 4 chunks, B: 2 chunks per thread)
#pragma unroll
    for (int s = 0; s < 4; ++s) {
        int row = s * 64 + srow8;
        int g = c8 ^ swc8(row);
        gl_lds16(&A[(size_t)(mbase + row) * HID + g * 8], &a_lds[0][(s * 64 + wave * 8) * 64]);
    }
#pragma unroll
    for (int s = 0; s < 2; ++s) {
        int row = s * 64 + srow8;
        int g = c8 ^ swc8(row);
        gl_lds16(&W[(size_t)(nbase + row) * HID + g * 8], &b_lds[0][(s * 64 + wave * 8) * 64]);
    }

    const int NT = HID / 64;   // 32 K-tiles
    for (int t = 0; t < NT; ++t) {
        const int buf = t & 1;
        __syncthreads();                 // tile t staged (vmcnt drain); prev reads done

        const short* al = a_lds[buf];
        const short* bl = b_lds[buf];
        const int nb  = buf ^ 1;
        const int kb1 = (t + 1) * 64;
        const bool pf = (t + 1 < NT);

        // B fragments for this K-tile (held across all 4 phases)
        short8 bfr[2][2];
#pragma unroll
        for (int nf = 0; nf < 2; ++nf) {
            int row = wn * 32 + nf * 16 + l15;
#pragma unroll
            for (int kk = 0; kk < 2; ++kk)
                bfr[nf][kk] = *(const short8*)&bl[row * 64 + ((kk * 32 + quad * 8) ^ (swc8(row) << 3))];
        }

#pragma unroll
        for (int ph = 0; ph < 4; ++ph) {
            if (pf) {                    // spread tile t+1 staging over phases 1..3
                if (ph == 1) {
#pragma unroll
                    for (int s = 0; s < 2; ++s) {
                        int row = s * 64 + srow8;
                        int g = c8 ^ swc8(row);
                        gl_lds16(&A[(size_t)(mbase + row) * HID + kb1 + g * 8],
                                 &a_lds[nb][(s * 64 + wave * 8) * 64]);
                    }
                } else if (ph == 2) {
#pragma unroll
                    for (int s = 2; s < 4; ++s) {
                        int row = s * 64 + srow8;
                        int g = c8 ^ swc8(row);
                        gl_lds16(&A[(size_t)(mbase + row) * HID + kb1 + g * 8],
                                 &a_lds[nb][(s * 64 + wave * 8) * 64]);
                    }
                } else if (ph == 3) {
#pragma unroll
                    for (int s = 0; s < 2; ++s) {
                        int row = s * 64 + srow8;
                        int g = c8 ^ swc8(row);
                        gl_lds16(&W[(size_t)(nbase + row) * HID + kb1 + g * 8],
                                 &b_lds[nb][(s * 64 + wave * 8) * 64]);
                    }
                }
            }
            // A fragments: this phase's 2 m-tiles
            short8 afr[2][2];
#pragma unroll
            for (int mi = 0; mi < 2; ++mi) {
                int row = wm * 128 + (ph * 2 + mi) * 16 + l15;
#pragma unroll
                for (int kk = 0; kk < 2; ++kk)
                    afr[mi][kk] = *(const short8*)&al[row * 64 + ((kk * 32 + quad * 8) ^ (swc8(row) << 3))];
            }
            __builtin_amdgcn_s_barrier();         // scheduling-only (no data crosses)
            __builtin_amdgcn_s_setprio(1);
#pragma unroll
            for (int mi = 0; mi < 2; ++mi)
#pragma unroll
                for (int nf = 0; nf < 2; ++nf)
#pragma unroll
                    for (int kk = 0; kk < 2; ++kk)
                        acc[ph * 2 + mi][nf] = mfma16(afr[mi][kk], bfr[nf][kk], acc[ph * 2 + mi][nf]);
            __builtin_amdgcn_s_setprio(0);
            __builtin_amdgcn_s_barrier();
        }
    }

    // epilogue: f32 C writes (coalesced over l15)
#pragma unroll
    for (int mf = 0; mf < 8; ++mf)
#pragma unroll
        for (int nf = 0; nf < 2; ++nf) {
            int n = nbase + wn * 32 + nf * 16 + l15;
#pragma unroll
            for (int r = 0; r < 4; ++r) {
                int m = mbase + wm * 128 + mf * 16 + quad * 4 + r;
                C[(size_t)m * HID + n] = acc[mf][nf][r];
            }
        }
}

// ---------- Causal flash attention, GQA, work-stealing, double-buffered K/V ----------
// Round-2 kernel verbatim (best measured flash: 68.5us, occ 19, 2 blk/CU).
__global__ __launch_bounds__(256, 2) void flash_attn(
    const short* __restrict__ Q, const short* __restrict__ K,
    const short* __restrict__ Vt, short* __restrict__ O, int* __restrict__ counter)
{
    __shared__ __align__(16) short k_lds[2][64 * 128];
    __shared__ __align__(16) short vt_lds[2][128 * 64];
    __shared__ __align__(16) short p_lds[4 * 32 * 40];
    __shared__ int s_item;

    const int tid  = threadIdx.x;
    const int lane = tid & 63;
    const int wave = tid >> 6;
    const int quad = lane >> 4;
    const int l15  = lane & 15;
    const int rh   = wave & 1;          // row half (32 rows)
    const int kh   = wave >> 1;         // key half (32 keys)
    const float c2 = 0.12751743f;       // (1/sqrt(128)) * log2(e)

    short8 ones;
#pragma unroll
    for (int j = 0; j < 8; ++j) ones[j] = (short)0x3F80;   // bf16 1.0

    const int krow_w = tid >> 4;        // 0..15 across block
    const int kg0    = lane & 15;
    const int vrow_w = tid >> 3;        // 0..31 across block
    const int vg0    = lane & 7;

    for (;;) {
        if (tid == 0) s_item = atomicAdd(counter, 1);
        __syncthreads();                // also fences previous item's buffer use
        const int item = s_item;
        if (item >= 1024) return;

        const int qtile = 31 - (item >> 5);    // heavy first (LPT)
        const int bh = item & 31;
        const int h  = bh & 15;
        const int b  = bh >> 4;
        const int kvh = h >> 2;
        const int qt  = qtile * 64;
        const short* Kb  = &K[(size_t)(b * SEQ) * KVD + kvh * HD];
        const short* Vtb = &Vt[((size_t)(b * NKV + kvh) * HD) * SEQ];

        // Q fragments (A-layout): 32 rows per wave (2 m-subtiles), 4 k-steps
        short8 qf[2][4];
#pragma unroll
        for (int mi = 0; mi < 2; ++mi)
#pragma unroll
            for (int ks = 0; ks < 4; ++ks)
                qf[mi][ks] = *(const short8*)&Q[(size_t)(b * SEQ + qt + rh * 32 + mi * 16 + l15) * HID
                                                + h * HD + ks * 32 + quad * 8];

        f4 o_acc[2][8] = {};
        f4 o_sum[2] = {};

        const int nkb = qtile + 1;
        // stage tile 0 into buffer 0 (block-cooperative: 4 waves)
#pragma unroll
        for (int s = 0; s < 4; ++s) {
            int row = s * 16 + krow_w;
            gl_lds16(&Kb[(size_t)row * KVD + ((kg0 ^ (row & 15)) * 8)],
                     &k_lds[0][(s * 16 + wave * 4) * 128]);
        }
#pragma unroll
        for (int s = 0; s < 4; ++s) {
            int row = s * 32 + vrow_w;
            gl_lds16(&Vtb[(size_t)row * SEQ + ((vg0 ^ swc8(row)) * 8)],
                     &vt_lds[0][(s * 32 + wave * 8) * 64]);
        }

        for (int kb = 0; kb < nkb; ++kb) {
            const int buf = kb & 1;
            __syncthreads();               // staging for kb complete; prev compute done

            if (kb + 1 < nkb) {            // prefetch kb+1 into the other buffer
                const int s0n = (kb + 1) * 64;
                const int nb = buf ^ 1;
#pragma unroll
                for (int s = 0; s < 4; ++s) {
                    int row = s * 16 + krow_w;
                    gl_lds16(&Kb[(size_t)(s0n + row) * KVD + ((kg0 ^ (row & 15)) * 8)],
                             &k_lds[nb][(s * 16 + wave * 4) * 128]);
                }
#pragma unroll
                for (int s = 0; s < 4; ++s) {
                    int row = s * 32 + vrow_w;
                    gl_lds16(&Vtb[(size_t)row * SEQ + s0n + ((vg0 ^ swc8(row)) * 8)],
                             &vt_lds[nb][(s * 32 + wave * 8) * 64]);
                }
            }

            const bool diag = (kb == nkb - 1);
            // wave 2 = (rows 0..31, keys 32..63): fully masked on diagonal tile; skip.
            if (!(diag && wave == 2)) {
                const short* kl = k_lds[buf];
                const short* vl = vt_lds[buf];

                // S = Q K^T : 32 rows x 32 keys per wave
                f4 sc[2][2] = {};
                __builtin_amdgcn_s_setprio(1);
#pragma unroll
                for (int t = 0; t < 2; ++t)
#pragma unroll
                    for (int ks = 0; ks < 4; ++ks) {
                        int krow = kh * 32 + t * 16 + l15;
                        short8 kf = *(const short8*)&kl[krow * 128 + ((ks * 32 + quad * 8) ^ ((krow & 15) << 3))];
                        sc[0][t] = mfma16(qf[0][ks], kf, sc[0][t]);
                        sc[1][t] = mfma16(qf[1][ks], kf, sc[1][t]);
                    }
                __builtin_amdgcn_s_setprio(0);

                // unnormalized softmax: p = exp2(s*c2); mask only on the diagonal tile
                const int s0 = kb * 64;
                short* pw = &p_lds[wave * 32 * 40];
#pragma unroll
                for (int mi = 0; mi < 2; ++mi)
#pragma unroll
                    for (int t = 0; t < 2; ++t) {
                        int kcol = s0 + kh * 32 + t * 16 + l15;
#pragma unroll
                        for (int r = 0; r < 4; ++r) {
                            float e = __builtin_amdgcn_exp2f(sc[mi][t][r] * c2);
                            if (diag) {
                                int qg = qt + rh * 32 + mi * 16 + quad * 4 + r;
                                e = (kcol <= qg) ? e : 0.0f;
                            }
                            pw[(mi * 16 + quad * 4 + r) * 40 + t * 16 + l15] = f2b(e);
                        }
                    }

                // P fragments (A-layout, k=32 keys); row sums via MFMA against ones
                short8 pf[2];
#pragma unroll
                for (int mi = 0; mi < 2; ++mi)
                    pf[mi] = *(const short8*)&pw[(mi * 16 + l15) * 40 + quad * 8];
                o_sum[0] = mfma16(pf[0], ones, o_sum[0]);
                o_sum[1] = mfma16(pf[1], ones, o_sum[1]);

                // O += P V  (key-half partial)
                __builtin_amdgcn_s_setprio(1);
#pragma unroll
                for (int nt = 0; nt < 8; ++nt) {
                    int vrow = nt * 16 + l15;
                    short8 vf = *(const short8*)&vl[vrow * 64 + ((kh * 32 + quad * 8) ^ (swc8(vrow) << 3))];
                    o_acc[0][nt] = mfma16(pf[0], vf, o_acc[0][nt]);
                    o_acc[1][nt] = mfma16(pf[1], vf, o_acc[1][nt]);
                }
                __builtin_amdgcn_s_setprio(0);
            }
        }

        // ---- combine key-half partials (linear: unnormalized softmax) ----
        __syncthreads();                   // all compute done; k_lds/p_lds reusable
        float* xo = (float*)&k_lds[0][0];  // 8192 floats = 32KB
        float* xs = (float*)&p_lds[0];
        if (wave >= 2) {
            const int wr = wave - 2;
#pragma unroll
            for (int mi = 0; mi < 2; ++mi)
#pragma unroll
                for (int nt = 0; nt < 8; ++nt)
                    *(f4*)&xo[wr * 4096 + (mi * 8 + nt) * 256 + lane * 4] = o_acc[mi][nt];
#pragma unroll
            for (int mi = 0; mi < 2; ++mi)
                *(f4*)&xs[wr * 512 + mi * 256 + lane * 4] = o_sum[mi];
        }
        __syncthreads();
        if (wave < 2) {
#pragma unroll
            for (int mi = 0; mi < 2; ++mi)
#pragma unroll
                for (int nt = 0; nt < 8; ++nt)
                    o_acc[mi][nt] += *(const f4*)&xo[wave * 4096 + (mi * 8 + nt) * 256 + lane * 4];
#pragma unroll
            for (int mi = 0; mi < 2; ++mi)
                o_sum[mi] += *(const f4*)&xs[wave * 512 + mi * 256 + lane * 4];

            float inv[2][4];
#pragma unroll
            for (int mi = 0; mi < 2; ++mi)
#pragma unroll
                for (int r = 0; r < 4; ++r)
                    inv[mi][r] = 1.0f / o_sum[mi][r];

#pragma unroll
            for (int mi = 0; mi < 2; ++mi)
#pragma unroll
                for (int nt = 0; nt < 8; ++nt)
#pragma unroll
                    for (int r = 0; r < 4; ++r) {
                        int qg = qt + wave * 32 + mi * 16 + quad * 4 + r;
                        O[(size_t)(b * SEQ + qg) * HID + h * HD + nt * 16 + l15] =
                            f2b(o_acc[mi][nt][r] * inv[mi][r]);
                    }
        }
        // loop-top __syncthreads() fences xo reads vs next item's staging
    }
}

// ---------- launch ----------
extern "C" void kernel_launch(void* const* d_in, const int* in_sizes, int n_in,
                              void* d_out, int out_size, void* d_ws, size_t ws_size,
                              hipStream_t stream)
{
    const float* X  = (const float*)d_in[0];
    const float* Wq = (const float*)d_in[2];
    const float* bq = (const float*)d_in[3];
    const float* Wk = (const float*)d_in[4];
    const float* bk = (const float*)d_in[5];
    const float* Wv = (const float*)d_in[6];
    const float* bv = (const float*)d_in[7];
    const float* Wo = (const float*)d_in[8];

    // d_out (33.55 MB) doubles as scratch until out_gemm8:
    //   [0 .. 29,360,128)           converted X, Wq, Wk, Wv (bf16)
    //   [29,360,128 .. 30,408,704)  RoPE cos/sin table (2048 x 64 float2 = 1MB)
    //   [31,000,000 .. +4)          flash work-stealing counter (reset by cvt4)
    short* xb  = (short*)d_out;                // 8,388,608 shorts
    short* wqb = xb + 8388608;                 // 4,194,304
    short* wkb = wqb + 4194304;                // 1,048,576
    short* wvb = wkb + 1048576;                // 1,048,576  (ends at short 14,680,064)
    float* tab = (float*)((char*)d_out + 29360128);
    int*   cnt = (int*)((char*)d_out + 31000000);
    // ws: 42 MB
    short* q_ws  = (short*)d_ws;               // 8,388,608
    short* k_ws  = q_ws + 8388608;             // 2,097,152
    short* vt_ws = k_ws + 2097152;             // 2,097,152
    short* a_ws  = vt_ws + 2097152;            // 8,388,608
    short* wob   = q_ws;                       // alias: q dead after flash

    const int rows = BATCH * SEQ;              // 4096
    dim3 blk(256);

    // fused f32 -> bf16 conversion of X, Wq, Wk, Wv + trig-table fill + counter reset
    cvt4_kernel<<<dim3(7168), blk, 0, stream>>>(X, Wq, Wk, Wv, xb, tab, cnt);

    // fused QKV projection + RoPE (V written transposed; Q/K rotated in epilogue)
    qkv_gemm<<<dim3(24, rows / 128), blk, 0, stream>>>(xb, wqb, wkb, wvb, bq, bk, bv,
                                                       q_ws, k_ws, vt_ws, tab);

    // causal GQA flash attention (quadrant waves, work-stealing, double-buffered K/V)
    flash_attn<<<dim3(512), dim3(256), 0, stream>>>(q_ws, k_ws, vt_ws, a_ws, cnt);

    // convert Wo into the dead Q buffer, then 8-phase output projection -> f32 d_out
    cvt_kernel<<<dim3(4194304 / 8 / 256), blk, 0, stream>>>(Wo, wob, 4194304 / 8);
    out_gemm8<<<dim3(16, 16), dim3(512), 0, stream>>>(a_ws, wob, (float*)d_out);
}

// Round 11
// 284.999 us; speedup vs baseline: 1.1047x; 1.1047x over previous
//
#include <hip/hip_runtime.h>
#include <hip/hip_bf16.h>
#include <cstddef>
#include <cstdint>

// ---------- types / helpers ----------
typedef short short8 __attribute__((ext_vector_type(8)));
typedef __bf16 bf16x8 __attribute__((ext_vector_type(8)));
typedef float f4 __attribute__((ext_vector_type(4)));

__device__ __forceinline__ short f2b(float f) {
    __hip_bfloat16 h = __float2bfloat16(f);
    return __builtin_bit_cast(short, h);
}
__device__ __forceinline__ f4 mfma16(short8 a, short8 b, f4 c) {
    return __builtin_amdgcn_mfma_f32_16x16x32_bf16(
        __builtin_bit_cast(bf16x8, a), __builtin_bit_cast(bf16x8, b), c, 0, 0, 0);
}
__device__ __forceinline__ float b2f(short s) {
    unsigned u = ((unsigned)(unsigned short)s) << 16;
    return __builtin_bit_cast(float, u);
}
// async 16B/lane global->LDS (lds dest = wave-uniform base + lane*16)
__device__ __forceinline__ void gl_lds16(const void* g, void* l) {
    __builtin_amdgcn_global_load_lds(
        (const __attribute__((address_space(1))) unsigned*)g,
        (__attribute__((address_space(3))) unsigned*)l, 16, 0, 0);
}
// XOR swizzle on 8-short (16B) chunk index
__device__ __forceinline__ int swc8(int row) { return (row ^ (row >> 3)) & 7; }

// Problem constants
#define BATCH 2
#define SEQ   2048
#define HID   2048
#define NH    16
#define NKV   4
#define HD    128
#define KVD   512

// ---------- fused f32 -> bf16 convert of X, Wq, Wk, Wv + RoPE trig table + counter reset ----------
__global__ void cvt4_kernel(const float* __restrict__ X,  const float* __restrict__ Wq,
                            const float* __restrict__ Wk, const float* __restrict__ Wv,
                            short* __restrict__ dst, float* __restrict__ tab,
                            int* __restrict__ cnt)
{
    int i = blockIdx.x * 256 + threadIdx.x;        // chunk of 8 elems; 1,835,008 total
    if (i == 0) *cnt = 0;                          // flash work-stealing counter reset
    if (i < SEQ * 64) {                            // fill cos/sin table [pos][j] (131072)
        int pos = i >> 6, jj = i & 63;
        float invf = exp2f(-(float)jj * (19.931568569324174f / 64.0f)); // theta^(-j/64)
        float ang  = (float)pos * invf;
        float sn, cs;
        sincosf(ang, &sn, &cs);
        ((float2*)tab)[i] = make_float2(cs, sn);
    }
    const float* src; int si;
    if (i < 1048576)      { src = X;  si = i; }
    else if (i < 1572864) { src = Wq; si = i - 1048576; }
    else if (i < 1703936) { src = Wk; si = i - 1572864; }
    else                  { src = Wv; si = i - 1703936; }
    f4 v0 = *(const f4*)&src[si * 8];
    f4 v1 = *(const f4*)&src[si * 8 + 4];
    short8 r;
#pragma unroll
    for (int j = 0; j < 4; ++j) { r[j] = f2b(v0[j]); r[4 + j] = f2b(v1[j]); }
    *(short8*)&dst[(size_t)i * 8] = r;
}

__global__ void cvt_kernel(const float* __restrict__ src, short* __restrict__ dst, int n8)
{
    int i = blockIdx.x * 256 + threadIdx.x;
    if (i >= n8) return;
    f4 v0 = *(const f4*)&src[i * 8];
    f4 v1 = *(const f4*)&src[i * 8 + 4];
    short8 r;
#pragma unroll
    for (int j = 0; j < 4; ++j) { r[j] = f2b(v0[j]); r[4 + j] = f2b(v1[j]); }
    *(short8*)&dst[i * 8] = r;
}

// ---------- shared GEMM mainloop (m97-class): 128x128 tile, gl_lds + src-permuted swizzle ----------
__device__ __forceinline__ void gemm_core(
    const short* __restrict__ A, const short* __restrict__ W, int K,
    int mbase, int nbase, short* a_lds, short* b_lds, f4 (*acc)[4])
{
    const int tid  = threadIdx.x;
    const int lane = tid & 63;
    const int wave = tid >> 6;
    const int quad = lane >> 4;
    const int l15  = lane & 15;
    const int wrow = (wave >> 1) * 64;
    const int wcol = (wave & 1) * 64;
    const int srow = wave * 8 + (lane >> 3);   // + s*32
    const int c8   = lane & 7;

    for (int kb = 0; kb < K; kb += 64) {
#pragma unroll
        for (int s = 0; s < 4; ++s) {
            int row = s * 32 + srow;
            int g   = c8 ^ swc8(row);
            gl_lds16(&A[(size_t)(mbase + row) * K + kb + g * 8], &a_lds[(s * 32 + wave * 8) * 64]);
            gl_lds16(&W[(size_t)(nbase + row) * K + kb + g * 8], &b_lds[(s * 32 + wave * 8) * 64]);
        }
        __syncthreads();
#pragma unroll
        for (int kk = 0; kk < 64; kk += 32) {
            short8 af[4], bf[4];
#pragma unroll
            for (int i = 0; i < 4; ++i) {
                int row = wrow + i * 16 + l15;
                af[i] = *(const short8*)&a_lds[row * 64 + ((kk + quad * 8) ^ (swc8(row) << 3))];
            }
#pragma unroll
            for (int j = 0; j < 4; ++j) {
                int row = wcol + j * 16 + l15;
                bf[j] = *(const short8*)&b_lds[row * 64 + ((kk + quad * 8) ^ (swc8(row) << 3))];
            }
#pragma unroll
            for (int i = 0; i < 4; ++i)
#pragma unroll
                for (int j = 0; j < 4; ++j)
                    acc[i][j] = mfma16(af[i], bf[j], acc[i][j]);
        }
        __syncthreads();
    }
}

// ---------- fused QKV projection + RoPE (Q/K) ----------
__global__ __launch_bounds__(256, 3) void qkv_gemm(
    const short* __restrict__ xb,
    const short* __restrict__ wqb, const short* __restrict__ wkb, const short* __restrict__ wvb,
    const float* __restrict__ bq, const float* __restrict__ bk, const float* __restrict__ bv,
    short* __restrict__ q_ws, short* __restrict__ k_ws, short* __restrict__ vt_ws,
    const float* __restrict__ tab)
{
    __shared__ short a_lds[128 * 64];
    __shared__ short b_lds[128 * 64];
    const int nblk = blockIdx.x;
    const short* W; const float* bias; int nb, mode;
    if (nblk < 16)      { W = wqb; bias = bq; nb = nblk;      mode = 0; }
    else if (nblk < 20) { W = wkb; bias = bk; nb = nblk - 16; mode = 1; }
    else                { W = wvb; bias = bv; nb = nblk - 20; mode = 2; }
    const int mbase = blockIdx.y * 128;
    const int nbase = nb * 128;

    f4 acc[4][4] = {};
    gemm_core(xb, W, HID, mbase, nbase, a_lds, b_lds, acc);

    const int lane = threadIdx.x & 63;
    const int wave = threadIdx.x >> 6;
    const int quad = lane >> 4;
    const int l15  = lane & 15;
    const int wrow = (wave >> 1) * 64;
    const int wcol = (wave & 1) * 64;

    float bb[4];
#pragma unroll
    for (int j = 0; j < 4; ++j) bb[j] = bias[nbase + wcol + j * 16 + l15];

    if (mode == 2) {           // V: write transposed vt[b][kvh][d][s]
#pragma unroll
        for (int i = 0; i < 4; ++i)
#pragma unroll
            for (int j = 0; j < 4; ++j) {
                int n = nbase + wcol + j * 16 + l15;
                int kvh = n >> 7, d = n & 127;
#pragma unroll
                for (int r = 0; r < 4; ++r) {
                    int m = mbase + wrow + i * 16 + quad * 4 + r;
                    int b = m >> 11, s = m & (SEQ - 1);
                    vt_ws[(((size_t)(b * NKV + kvh) * HD + d) << 11) + s] = f2b(acc[i][j][r] + bb[j]);
                }
            }
    } else {
        short* out = (mode == 0) ? q_ws : k_ws;
        const int N = (mode == 0) ? HID : KVD;
        const float2* tp = (const float2*)tab;

        // publish biased values (bf16) for the cross-wave half exchange:
        // col c<64 -> a_lds[m][c], c>=64 -> b_lds[m][c-64]
#pragma unroll
        for (int i = 0; i < 4; ++i)
#pragma unroll
            for (int j = 0; j < 4; ++j) {
                int c  = wcol + j * 16 + l15;
                short* sm = (c < 64) ? a_lds : b_lds;
                int cc = c & 63;
#pragma unroll
                for (int r = 0; r < 4; ++r) {
                    int ml = wrow + i * 16 + quad * 4 + r;
                    sm[ml * 64 + cc] = f2b(acc[i][j][r] + bb[j]);
                }
            }
        __syncthreads();

#pragma unroll
        for (int i = 0; i < 4; ++i)
#pragma unroll
            for (int j = 0; j < 4; ++j) {
                int c   = wcol + j * 16 + l15;      // d = n & 127
                int n   = nbase + c;
                int j64 = c & 63;
                const short* smp = (c < 64) ? b_lds : a_lds;   // partner half (c^64)
#pragma unroll
                for (int r = 0; r < 4; ++r) {
                    int ml  = wrow + i * 16 + quad * 4 + r;
                    int m   = mbase + ml;
                    int pos = m & (SEQ - 1);
                    float2 t2 = tp[pos * 64 + j64];
                    float own = acc[i][j][r] + bb[j];
                    float pv  = b2f(smp[ml * 64 + j64]);
                    float o   = (c < 64) ? (own * t2.x - pv * t2.y)
                                         : (own * t2.x + pv * t2.y);
                    out[(size_t)m * N + n] = f2b(o);
                }
            }
    }
}

// ---------- output projection: bf16 x bf16 -> f32 (proven 128x128 m97-class) ----------
// Reverted from the 8-phase 256x128 experiment (75us vs this kernel's ~40us).
// Root cause of the 8-phase failure: iter-top __syncthreads drains vmcnt to 0
// each K-tile (T4 counted-vmcnt omitted by design; m218: drain0 == 1-phase),
// and grid 256 = exactly 1 block/CU of lockstep waves -> zero latency hiding.
__global__ __launch_bounds__(256, 3) void out_gemm(
    const short* __restrict__ A, const short* __restrict__ W, float* __restrict__ C)
{
    __shared__ short a_lds[128 * 64];
    __shared__ short b_lds[128 * 64];
    const int mbase = blockIdx.y * 128;
    const int nbase = blockIdx.x * 128;
    f4 acc[4][4] = {};
    gemm_core(A, W, HID, mbase, nbase, a_lds, b_lds, acc);

    const int lane = threadIdx.x & 63;
    const int wave = threadIdx.x >> 6;
    const int quad = lane >> 4;
    const int l15  = lane & 15;
    const int wrow = (wave >> 1) * 64;
    const int wcol = (wave & 1) * 64;
#pragma unroll
    for (int i = 0; i < 4; ++i)
#pragma unroll
        for (int j = 0; j < 4; ++j) {
            int n = nbase + wcol + j * 16 + l15;
#pragma unroll
            for (int r = 0; r < 4; ++r) {
                int m = mbase + wrow + i * 16 + quad * 4 + r;
                C[(size_t)m * HID + n] = acc[i][j][r];
            }
        }
}

// ---------- Causal flash attention, GQA, work-stealing, double-buffered K/V ----------
// Round-2 kernel verbatim (best measured flash: ~69us, occ 19.4, 2 blk/CU).
__global__ __launch_bounds__(256, 2) void flash_attn(
    const short* __restrict__ Q, const short* __restrict__ K,
    const short* __restrict__ Vt, short* __restrict__ O, int* __restrict__ counter)
{
    __shared__ __align__(16) short k_lds[2][64 * 128];
    __shared__ __align__(16) short vt_lds[2][128 * 64];
    __shared__ __align__(16) short p_lds[4 * 32 * 40];
    __shared__ int s_item;

    const int tid  = threadIdx.x;
    const int lane = tid & 63;
    const int wave = tid >> 6;
    const int quad = lane >> 4;
    const int l15  = lane & 15;
    const int rh   = wave & 1;          // row half (32 rows)
    const int kh   = wave >> 1;         // key half (32 keys)
    const float c2 = 0.12751743f;       // (1/sqrt(128)) * log2(e)

    short8 ones;
#pragma unroll
    for (int j = 0; j < 8; ++j) ones[j] = (short)0x3F80;   // bf16 1.0

    const int krow_w = tid >> 4;        // 0..15 across block
    const int kg0    = lane & 15;
    const int vrow_w = tid >> 3;        // 0..31 across block
    const int vg0    = lane & 7;

    for (;;) {
        if (tid == 0) s_item = atomicAdd(counter, 1);
        __syncthreads();                // also fences previous item's buffer use
        const int item = s_item;
        if (item >= 1024) return;

        const int qtile = 31 - (item >> 5);    // heavy first (LPT)
        const int bh = item & 31;
        const int h  = bh & 15;
        const int b  = bh >> 4;
        const int kvh = h >> 2;
        const int qt  = qtile * 64;
        const short* Kb  = &K[(size_t)(b * SEQ) * KVD + kvh * HD];
        const short* Vtb = &Vt[((size_t)(b * NKV + kvh) * HD) * SEQ];

        // Q fragments (A-layout): 32 rows per wave (2 m-subtiles), 4 k-steps
        short8 qf[2][4];
#pragma unroll
        for (int mi = 0; mi < 2; ++mi)
#pragma unroll
            for (int ks = 0; ks < 4; ++ks)
                qf[mi][ks] = *(const short8*)&Q[(size_t)(b * SEQ + qt + rh * 32 + mi * 16 + l15) * HID
                                                + h * HD + ks * 32 + quad * 8];

        f4 o_acc[2][8] = {};
        f4 o_sum[2] = {};

        const int nkb = qtile + 1;
        // stage tile 0 into buffer 0 (block-cooperative: 4 waves)
#pragma unroll
        for (int s = 0; s < 4; ++s) {
            int row = s * 16 + krow_w;
            gl_lds16(&Kb[(size_t)row * KVD + ((kg0 ^ (row & 15)) * 8)],
                     &k_lds[0][(s * 16 + wave * 4) * 128]);
        }
#pragma unroll
        for (int s = 0; s < 4; ++s) {
            int row = s * 32 + vrow_w;
            gl_lds16(&Vtb[(size_t)row * SEQ + ((vg0 ^ swc8(row)) * 8)],
                     &vt_lds[0][(s * 32 + wave * 8) * 64]);
        }

        for (int kb = 0; kb < nkb; ++kb) {
            const int buf = kb & 1;
            __syncthreads();               // staging for kb complete; prev compute done

            if (kb + 1 < nkb) {            // prefetch kb+1 into the other buffer
                const int s0n = (kb + 1) * 64;
                const int nb = buf ^ 1;
#pragma unroll
                for (int s = 0; s < 4; ++s) {
                    int row = s * 16 + krow_w;
                    gl_lds16(&Kb[(size_t)(s0n + row) * KVD + ((kg0 ^ (row & 15)) * 8)],
                             &k_lds[nb][(s * 16 + wave * 4) * 128]);
                }
#pragma unroll
                for (int s = 0; s < 4; ++s) {
                    int row = s * 32 + vrow_w;
                    gl_lds16(&Vtb[(size_t)row * SEQ + s0n + ((vg0 ^ swc8(row)) * 8)],
                             &vt_lds[nb][(s * 32 + wave * 8) * 64]);
                }
            }

            const bool diag = (kb == nkb - 1);
            // wave 2 = (rows 0..31, keys 32..63): fully masked on diagonal tile; skip.
            if (!(diag && wave == 2)) {
                const short* kl = k_lds[buf];
                const short* vl = vt_lds[buf];

                // S = Q K^T : 32 rows x 32 keys per wave
                f4 sc[2][2] = {};
                __builtin_amdgcn_s_setprio(1);
#pragma unroll
                for (int t = 0; t < 2; ++t)
#pragma unroll
                    for (int ks = 0; ks < 4; ++ks) {
                        int krow = kh * 32 + t * 16 + l15;
                        short8 kf = *(const short8*)&kl[krow * 128 + ((ks * 32 + quad * 8) ^ ((krow & 15) << 3))];
                        sc[0][t] = mfma16(qf[0][ks], kf, sc[0][t]);
                        sc[1][t] = mfma16(qf[1][ks], kf, sc[1][t]);
                    }
                __builtin_amdgcn_s_setprio(0);

                // unnormalized softmax: p = exp2(s*c2); mask only on the diagonal tile
                const int s0 = kb * 64;
                short* pw = &p_lds[wave * 32 * 40];
#pragma unroll
                for (int mi = 0; mi < 2; ++mi)
#pragma unroll
                    for (int t = 0; t < 2; ++t) {
                        int kcol = s0 + kh * 32 + t * 16 + l15;
#pragma unroll
                        for (int r = 0; r < 4; ++r) {
                            float e = __builtin_amdgcn_exp2f(sc[mi][t][r] * c2);
                            if (diag) {
                                int qg = qt + rh * 32 + mi * 16 + quad * 4 + r;
                                e = (kcol <= qg) ? e : 0.0f;
                            }
                            pw[(mi * 16 + quad * 4 + r) * 40 + t * 16 + l15] = f2b(e);
                        }
                    }

                // P fragments (A-layout, k=32 keys); row sums via MFMA against ones
                short8 pf[2];
#pragma unroll
                for (int mi = 0; mi < 2; ++mi)
                    pf[mi] = *(const short8*)&pw[(mi * 16 + l15) * 40 + quad * 8];
                o_sum[0] = mfma16(pf[0], ones, o_sum[0]);
                o_sum[1] = mfma16(pf[1], ones, o_sum[1]);

                // O += P V  (key-half partial)
                __builtin_amdgcn_s_setprio(1);
#pragma unroll
                for (int nt = 0; nt < 8; ++nt) {
                    int vrow = nt * 16 + l15;
                    short8 vf = *(const short8*)&vl[vrow * 64 + ((kh * 32 + quad * 8) ^ (swc8(vrow) << 3))];
                    o_acc[0][nt] = mfma16(pf[0], vf, o_acc[0][nt]);
                    o_acc[1][nt] = mfma16(pf[1], vf, o_acc[1][nt]);
                }
                __builtin_amdgcn_s_setprio(0);
            }
        }

        // ---- combine key-half partials (linear: unnormalized softmax) ----
        __syncthreads();                   // all compute done; k_lds/p_lds reusable
        float* xo = (float*)&k_lds[0][0];  // 8192 floats = 32KB
        float* xs = (float*)&p_lds[0];
        if (wave >= 2) {
            const int wr = wave - 2;
#pragma unroll
            for (int mi = 0; mi < 2; ++mi)
#pragma unroll
                for (int nt = 0; nt < 8; ++nt)
                    *(f4*)&xo[wr * 4096 + (mi * 8 + nt) * 256 + lane * 4] = o_acc[mi][nt];
#pragma unroll
            for (int mi = 0; mi < 2; ++mi)
                *(f4*)&xs[wr * 512 + mi * 256 + lane * 4] = o_sum[mi];
        }
        __syncthreads();
        if (wave < 2) {
#pragma unroll
            for (int mi = 0; mi < 2; ++mi)
#pragma unroll
                for (int nt = 0; nt < 8; ++nt)
                    o_acc[mi][nt] += *(const f4*)&xo[wave * 4096 + (mi * 8 + nt) * 256 + lane * 4];
#pragma unroll
            for (int mi = 0; mi < 2; ++mi)
                o_sum[mi] += *(const f4*)&xs[wave * 512 + mi * 256 + lane * 4];

            float inv[2][4];
#pragma unroll
            for (int mi = 0; mi < 2; ++mi)
#pragma unroll
                for (int r = 0; r < 4; ++r)
                    inv[mi][r] = 1.0f / o_sum[mi][r];

#pragma unroll
            for (int mi = 0; mi < 2; ++mi)
#pragma unroll
                for (int nt = 0; nt < 8; ++nt)
#pragma unroll
                    for (int r = 0; r < 4; ++r) {
                        int qg = qt + wave * 32 + mi * 16 + quad * 4 + r;
                        O[(size_t)(b * SEQ + qg) * HID + h * HD + nt * 16 + l15] =
                            f2b(o_acc[mi][nt][r] * inv[mi][r]);
                    }
        }
        // loop-top __syncthreads() fences xo reads vs next item's staging
    }
}

// ---------- launch ----------
extern "C" void kernel_launch(void* const* d_in, const int* in_sizes, int n_in,
                              void* d_out, int out_size, void* d_ws, size_t ws_size,
                              hipStream_t stream)
{
    const float* X  = (const float*)d_in[0];
    const float* Wq = (const float*)d_in[2];
    const float* bq = (const float*)d_in[3];
    const float* Wk = (const float*)d_in[4];
    const float* bk = (const float*)d_in[5];
    const float* Wv = (const float*)d_in[6];
    const float* bv = (const float*)d_in[7];
    const float* Wo = (const float*)d_in[8];

    // d_out (33.55 MB) doubles as scratch until out_gemm:
    //   [0 .. 29,360,128)           converted X, Wq, Wk, Wv (bf16)
    //   [29,360,128 .. 30,408,704)  RoPE cos/sin table (2048 x 64 float2 = 1MB)
    //   [31,000,000 .. +4)          flash work-stealing counter (reset by cvt4)
    short* xb  = (short*)d_out;                // 8,388,608 shorts
    short* wqb = xb + 8388608;                 // 4,194,304
    short* wkb = wqb + 4194304;                // 1,048,576
    short* wvb = wkb + 1048576;                // 1,048,576  (ends at short 14,680,064)
    float* tab = (float*)((char*)d_out + 29360128);
    int*   cnt = (int*)((char*)d_out + 31000000);
    // ws: 42 MB
    short* q_ws  = (short*)d_ws;               // 8,388,608
    short* k_ws  = q_ws + 8388608;             // 2,097,152
    short* vt_ws = k_ws + 2097152;             // 2,097,152
    short* a_ws  = vt_ws + 2097152;            // 8,388,608
    short* wob   = q_ws;                       // alias: q dead after flash

    const int rows = BATCH * SEQ;              // 4096
    dim3 blk(256);

    // fused f32 -> bf16 conversion of X, Wq, Wk, Wv + trig-table fill + counter reset
    cvt4_kernel<<<dim3(7168), blk, 0, stream>>>(X, Wq, Wk, Wv, xb, tab, cnt);

    // fused QKV projection + RoPE (V written transposed; Q/K rotated in epilogue)
    qkv_gemm<<<dim3(24, rows / 128), blk, 0, stream>>>(xb, wqb, wkb, wvb, bq, bk, bv,
                                                       q_ws, k_ws, vt_ws, tab);

    // causal GQA flash attention (quadrant waves, work-stealing, double-buffered K/V)
    flash_attn<<<dim3(512), dim3(256), 0, stream>>>(q_ws, k_ws, vt_ws, a_ws, cnt);

    // convert Wo into the dead Q buffer, then output projection -> f32 d_out
    cvt_kernel<<<dim3(4194304 / 8 / 256), blk, 0, stream>>>(Wo, wob, 4194304 / 8);
    out_gemm<<<dim3(HID / 128, rows / 128), blk, 0, stream>>>(a_ws, wob, (float*)d_out);
}